// Round 1
// baseline (482.731 us; speedup 1.0000x reference)
//
#include <hip/hip_runtime.h>

typedef unsigned short u16;
typedef unsigned int u32;
typedef unsigned long long u64;
typedef float f32x4 __attribute__((ext_vector_type(4)));
typedef short short8 __attribute__((ext_vector_type(8)));

#define BB 4
#define SS 2048
#define EE 1024
#define HH 16
#define DD 64
#define NEGV (-1e9f)
#define EPSV 1e-5f

__device__ __forceinline__ u16 f2b(float x) {
  u32 u = __float_as_uint(x);
  u32 r = (u + 0x7fffu + ((u >> 16) & 1u)) >> 16;
  return (u16)r;
}
__device__ __forceinline__ float b2f(u16 u) {
  return __uint_as_float(((u32)u) << 16);
}

// ---------------- LayerNorm: 1 block per row of 1024 fp32 ----------------
template<bool OUT_BF16>
__global__ __launch_bounds__(256) void ln_kernel(const float* __restrict__ x,
    const float* __restrict__ gamma, const float* __restrict__ beta,
    void* __restrict__ outp) {
  int row = blockIdx.x;
  int t = threadIdx.x;
  const float4* xr = (const float4*)(x + (size_t)row * EE);
  float4 v = xr[t];
  float s = v.x + v.y + v.z + v.w;
  #pragma unroll
  for (int o = 1; o < 64; o <<= 1) s += __shfl_xor(s, o);
  __shared__ float red[8];
  int wid = t >> 6;
  if ((t & 63) == 0) red[wid] = s;
  __syncthreads();
  float mean = (red[0] + red[1] + red[2] + red[3]) * (1.0f / EE);
  float d0 = v.x - mean, d1 = v.y - mean, d2 = v.z - mean, d3 = v.w - mean;
  float sq = d0 * d0 + d1 * d1 + d2 * d2 + d3 * d3;
  #pragma unroll
  for (int o = 1; o < 64; o <<= 1) sq += __shfl_xor(sq, o);
  if ((t & 63) == 0) red[4 + wid] = sq;
  __syncthreads();
  float var = (red[4] + red[5] + red[6] + red[7]) * (1.0f / EE);
  float rstd = rsqrtf(var + EPSV);
  float4 g = ((const float4*)gamma)[t];
  float4 be = ((const float4*)beta)[t];
  float o0 = d0 * rstd * g.x + be.x;
  float o1 = d1 * rstd * g.y + be.y;
  float o2 = d2 * rstd * g.z + be.z;
  float o3 = d3 * rstd * g.w + be.w;
  if (OUT_BF16) {
    ushort4 pk;
    pk.x = f2b(o0); pk.y = f2b(o1); pk.z = f2b(o2); pk.w = f2b(o3);
    *(ushort4*)((u16*)outp + (size_t)row * EE + t * 4) = pk;
  } else {
    ((float4*)((float*)outp + (size_t)row * EE))[t] = make_float4(o0, o1, o2, o3);
  }
}

// ------------- W (K x N fp32) -> Wt (N x K bf16) via LDS 32x32 tile -------------
__global__ __launch_bounds__(256) void wtrans_kernel(const float* __restrict__ W,
    u16* __restrict__ Wt) {
  __shared__ float tile[32][33];
  int kb = blockIdx.x * 32, nb = blockIdx.y * 32;
  int t = threadIdx.x;
  int r = t >> 3, c = (t & 7) * 4;
  float4 v = *(const float4*)&W[(size_t)(kb + r) * EE + nb + c];
  tile[r][c] = v.x; tile[r][c + 1] = v.y; tile[r][c + 2] = v.z; tile[r][c + 3] = v.w;
  __syncthreads();
  uint2 val;
  val.x = (u32)f2b(tile[c][r]) | ((u32)f2b(tile[c + 1][r]) << 16);
  val.y = (u32)f2b(tile[c + 2][r]) | ((u32)f2b(tile[c + 3][r]) << 16);
  *(uint2*)&Wt[(size_t)(nb + r) * EE + kb + c] = val;
}

// ---------------- pack mask ints -> bit mask (1 bit per element) ----------------
__global__ __launch_bounds__(256) void maskpack_kernel(const int* __restrict__ mask,
    u64* __restrict__ mp) {
  int gid = blockIdx.x * 256 + threadIdx.x;
  int v = mask[gid];
  u64 bal = __ballot(v != 0);
  if ((threadIdx.x & 63) == 0) mp[gid >> 6] = bal;
}

// ---------------- GEMM: C = A @ Wt^T + bias ----------------
// A: M x K (fp32 if !ABF else bf16), Bt: N x K bf16 (pre-transposed weight)
// MODE 0: store bf16 C[m*N+n]
// MODE 1: store bf16 transposed per-head: vt[((b*H+h)*D+d)*S + s]
// MODE 2: store fp32 C[m*N+n] = acc + bias + residual(bf16)
template<bool ABF, int MODE>
__global__ __launch_bounds__(256) void gemm_kernel(const void* __restrict__ Ap,
    const u16* __restrict__ Bt, const float* __restrict__ bias,
    const u16* __restrict__ resid, void* __restrict__ Cp) {
  constexpr int N = 1024, K = 1024;
  __shared__ u16 Al[128][40];
  __shared__ u16 Bl[128][40];
  int t = threadIdx.x;
  int lane = t & 63, wid = t >> 6;
  int mb = blockIdx.y * 128, nb = blockIdx.x * 128;
  int wm = (wid >> 1) * 64, wn = (wid & 1) * 64;
  int lrow = t >> 1, lcol = (t & 1) * 16;
  int l15 = lane & 15, lg = lane >> 4;
  int kof = lg * 8;
  f32x4 acc[4][4] = {};
  for (int kt = 0; kt < K; kt += 32) {
    if (ABF) {
      const u16* Ab = (const u16*)Ap + (size_t)(mb + lrow) * K + kt + lcol;
      *(uint4*)&Al[lrow][lcol] = *(const uint4*)Ab;
      *(uint4*)&Al[lrow][lcol + 8] = *(const uint4*)(Ab + 8);
    } else {
      const float* Af = (const float*)Ap + (size_t)(mb + lrow) * K + kt + lcol;
      float4 f0 = *(const float4*)(Af + 0);
      float4 f1 = *(const float4*)(Af + 4);
      float4 f2 = *(const float4*)(Af + 8);
      float4 f3 = *(const float4*)(Af + 12);
      uint4 pk0, pk1;
      pk0.x = (u32)f2b(f0.x) | ((u32)f2b(f0.y) << 16);
      pk0.y = (u32)f2b(f0.z) | ((u32)f2b(f0.w) << 16);
      pk0.z = (u32)f2b(f1.x) | ((u32)f2b(f1.y) << 16);
      pk0.w = (u32)f2b(f1.z) | ((u32)f2b(f1.w) << 16);
      pk1.x = (u32)f2b(f2.x) | ((u32)f2b(f2.y) << 16);
      pk1.y = (u32)f2b(f2.z) | ((u32)f2b(f2.w) << 16);
      pk1.z = (u32)f2b(f3.x) | ((u32)f2b(f3.y) << 16);
      pk1.w = (u32)f2b(f3.z) | ((u32)f2b(f3.w) << 16);
      *(uint4*)&Al[lrow][lcol] = pk0;
      *(uint4*)&Al[lrow][lcol + 8] = pk1;
    }
    {
      const u16* Bp = Bt + (size_t)(nb + lrow) * K + kt + lcol;
      *(uint4*)&Bl[lrow][lcol] = *(const uint4*)Bp;
      *(uint4*)&Bl[lrow][lcol + 8] = *(const uint4*)(Bp + 8);
    }
    __syncthreads();
    short8 af[4], bfv[4];
    #pragma unroll
    for (int mf = 0; mf < 4; mf++) af[mf] = *(const short8*)&Al[wm + mf * 16 + l15][kof];
    #pragma unroll
    for (int nf = 0; nf < 4; nf++) bfv[nf] = *(const short8*)&Bl[wn + nf * 16 + l15][kof];
    #pragma unroll
    for (int mf = 0; mf < 4; mf++)
      #pragma unroll
      for (int nf = 0; nf < 4; nf++)
        acc[mf][nf] = __builtin_amdgcn_mfma_f32_16x16x32_bf16(af[mf], bfv[nf], acc[mf][nf], 0, 0, 0);
    __syncthreads();
  }
  float bv[4];
  #pragma unroll
  for (int nf = 0; nf < 4; nf++) bv[nf] = bias[nb + wn + nf * 16 + l15];
  #pragma unroll
  for (int mf = 0; mf < 4; mf++) {
    #pragma unroll
    for (int r = 0; r < 4; r++) {
      int m = mb + wm + mf * 16 + lg * 4 + r;
      #pragma unroll
      for (int nf = 0; nf < 4; nf++) {
        int n = nb + wn + nf * 16 + l15;
        float val = acc[mf][nf][r] + bv[nf];
        if (MODE == 0) {
          ((u16*)Cp)[(size_t)m * N + n] = f2b(val);
        } else if (MODE == 1) {
          int b = m >> 11, s = m & 2047;
          int h = n >> 6, d = n & 63;
          ((u16*)Cp)[((size_t)((b * HH + h) * DD + d)) * SS + s] = f2b(val);
        } else {
          float rv = b2f(resid[(size_t)m * N + n]);
          ((float*)Cp)[(size_t)m * N + n] = val + rv;
        }
      }
    }
  }
}

// ---------------- flash attention ----------------
// grid: (S/64, B*H); 4 waves, each owns 16 q rows. KT = 64.
__global__ __launch_bounds__(256) void attn_kernel(const u16* __restrict__ qh,
    const u16* __restrict__ kh, const u16* __restrict__ vt,
    const u64* __restrict__ mp, u16* __restrict__ outp) {
  __shared__ u16 Kl[64][72];
  __shared__ u16 Vl[64][72];
  __shared__ u16 Pl[4][16][72];
  int t = threadIdx.x, lane = t & 63, wid = t >> 6;
  int bh = blockIdx.y, b = bh >> 4, h = bh & 15;
  int qt = blockIdx.x;
  int l15 = lane & 15, lg = lane >> 4;
  int kof = lg * 8;
  int qrow = qt * 64 + wid * 16 + l15;
  const u16* qbase = qh + ((size_t)(b * SS + qrow)) * EE + h * DD;
  short8 qf0 = *(const short8*)(qbase + kof);
  short8 qf1 = *(const short8*)(qbase + 32 + kof);
  f32x4 O[4] = {};
  float mi[4], li[4];
  #pragma unroll
  for (int r = 0; r < 4; r++) { mi[r] = -3.0e38f; li[r] = 0.f; }
  int lrow = t >> 2, lcol = (t & 3) * 16;
  for (int kt = 0; kt < SS / 64; ++kt) {
    const u16* kp = kh + ((size_t)(b * SS + kt * 64 + lrow)) * EE + h * DD + lcol;
    *(uint4*)&Kl[lrow][lcol] = *(const uint4*)kp;
    *(uint4*)&Kl[lrow][lcol + 8] = *(const uint4*)(kp + 8);
    const u16* vp = vt + ((size_t)((b * HH + h) * DD + lrow)) * SS + kt * 64 + lcol;
    *(uint4*)&Vl[lrow][lcol] = *(const uint4*)vp;
    *(uint4*)&Vl[lrow][lcol + 8] = *(const uint4*)(vp + 8);
    __syncthreads();
    f32x4 sc[4];
    #pragma unroll
    for (int nf = 0; nf < 4; nf++) {
      short8 k0 = *(const short8*)&Kl[nf * 16 + l15][kof];
      short8 k1 = *(const short8*)&Kl[nf * 16 + l15][32 + kof];
      f32x4 z = {};
      z = __builtin_amdgcn_mfma_f32_16x16x32_bf16(qf0, k0, z, 0, 0, 0);
      z = __builtin_amdgcn_mfma_f32_16x16x32_bf16(qf1, k1, z, 0, 0, 0);
      sc[nf] = z;
    }
    #pragma unroll
    for (int r = 0; r < 4; r++) {
      int qr = qt * 64 + wid * 16 + lg * 4 + r;
      u64 mw = mp[(size_t)(b * SS + qr) * (SS / 64) + kt];
      #pragma unroll
      for (int nf = 0; nf < 4; nf++)
        if ((mw >> (nf * 16 + l15)) & 1ull) sc[nf][r] = NEGV;
    }
    #pragma unroll
    for (int r = 0; r < 4; r++) {
      float mx = fmaxf(fmaxf(sc[0][r], sc[1][r]), fmaxf(sc[2][r], sc[3][r]));
      mx = fmaxf(mx, __shfl_xor(mx, 1));
      mx = fmaxf(mx, __shfl_xor(mx, 2));
      mx = fmaxf(mx, __shfl_xor(mx, 4));
      mx = fmaxf(mx, __shfl_xor(mx, 8));
      float mnew = fmaxf(mi[r], mx);
      float scale = __expf(mi[r] - mnew);
      mi[r] = mnew;
      float rs = 0.f;
      #pragma unroll
      for (int nf = 0; nf < 4; nf++) {
        float p = __expf(sc[nf][r] - mnew);
        sc[nf][r] = p;
        rs += p;
      }
      rs += __shfl_xor(rs, 1);
      rs += __shfl_xor(rs, 2);
      rs += __shfl_xor(rs, 4);
      rs += __shfl_xor(rs, 8);
      li[r] = li[r] * scale + rs;
      #pragma unroll
      for (int nf = 0; nf < 4; nf++) O[nf][r] *= scale;
    }
    #pragma unroll
    for (int r = 0; r < 4; r++)
      #pragma unroll
      for (int nf = 0; nf < 4; nf++)
        Pl[wid][lg * 4 + r][nf * 16 + l15] = f2b(sc[nf][r]);
    __syncthreads();
    short8 pf0 = *(const short8*)&Pl[wid][l15][kof];
    short8 pf1 = *(const short8*)&Pl[wid][l15][32 + kof];
    #pragma unroll
    for (int nf = 0; nf < 4; nf++) {
      short8 v0 = *(const short8*)&Vl[nf * 16 + l15][kof];
      short8 v1 = *(const short8*)&Vl[nf * 16 + l15][32 + kof];
      O[nf] = __builtin_amdgcn_mfma_f32_16x16x32_bf16(pf0, v0, O[nf], 0, 0, 0);
      O[nf] = __builtin_amdgcn_mfma_f32_16x16x32_bf16(pf1, v1, O[nf], 0, 0, 0);
    }
    __syncthreads();
  }
  #pragma unroll
  for (int r = 0; r < 4; r++) {
    float inv = 1.0f / li[r];
    int qr = qt * 64 + wid * 16 + lg * 4 + r;
    #pragma unroll
    for (int nf = 0; nf < 4; nf++) {
      outp[((size_t)(b * SS + qr)) * EE + h * DD + nf * 16 + l15] = f2b(O[nf][r] * inv);
    }
  }
}

extern "C" void kernel_launch(void* const* d_in, const int* in_sizes, int n_in,
                              void* d_out, int out_size, void* d_ws, size_t ws_size,
                              hipStream_t stream) {
  (void)in_sizes; (void)n_in; (void)out_size; (void)ws_size;
  const float* q    = (const float*)d_in[0];
  const float* k    = (const float*)d_in[1];
  const float* v    = (const float*)d_in[2];
  const int*   mask = (const int*)d_in[3];
  const float* W1   = (const float*)d_in[4];
  const float* b1   = (const float*)d_in[5];
  const float* W2   = (const float*)d_in[6];
  const float* b2   = (const float*)d_in[7];
  const float* W3   = (const float*)d_in[8];
  const float* b3   = (const float*)d_in[9];
  const float* W4   = (const float*)d_in[10];
  const float* b4   = (const float*)d_in[11];
  const float* gamma = (const float*)d_in[12];
  const float* beta  = (const float*)d_in[13];
  float* out = (float*)d_out;
  char* ws = (char*)d_ws;
  const size_t MB = 1024 * 1024;
  u16* qh  = (u16*)(ws + 0 * MB);
  u16* kh  = (u16*)(ws + 16 * MB);
  u16* vt  = (u16*)(ws + 32 * MB);
  u16* ao  = (u16*)(ws + 48 * MB);
  u16* vn  = (u16*)(ws + 64 * MB);
  u16* W1t = (u16*)(ws + 80 * MB);
  u16* W2t = (u16*)(ws + 82 * MB);
  u16* W3t = (u16*)(ws + 84 * MB);
  u16* W4t = (u16*)(ws + 86 * MB);
  u64* mp  = (u64*)(ws + 88 * MB);
  float* tmp = (float*)(ws + 0 * MB);  // overlays qh+kh (dead by then)

  wtrans_kernel<<<dim3(32, 32), 256, 0, stream>>>(W1, W1t);
  wtrans_kernel<<<dim3(32, 32), 256, 0, stream>>>(W2, W2t);
  wtrans_kernel<<<dim3(32, 32), 256, 0, stream>>>(W3, W3t);
  wtrans_kernel<<<dim3(32, 32), 256, 0, stream>>>(W4, W4t);
  maskpack_kernel<<<65536, 256, 0, stream>>>(mask, mp);
  ln_kernel<true><<<8192, 256, 0, stream>>>(v, gamma, beta, vn);
  gemm_kernel<false, 0><<<dim3(8, 64), 256, 0, stream>>>(q, W1t, b1, nullptr, qh);
  gemm_kernel<false, 0><<<dim3(8, 64), 256, 0, stream>>>(k, W2t, b2, nullptr, kh);
  gemm_kernel<true, 1><<<dim3(8, 64), 256, 0, stream>>>(vn, W3t, b3, nullptr, vt);
  attn_kernel<<<dim3(32, 64), 256, 0, stream>>>(qh, kh, vt, mp, ao);
  gemm_kernel<true, 2><<<dim3(8, 64), 256, 0, stream>>>(ao, W4t, b4, vn, tmp);
  ln_kernel<false><<<8192, 256, 0, stream>>>(tmp, gamma, beta, out);
}

// Round 3
// 394.467 us; speedup vs baseline: 1.2238x; 1.2238x over previous
//
#include <hip/hip_runtime.h>

typedef unsigned short u16;
typedef unsigned int u32;
typedef unsigned long long u64;
typedef float f32x4 __attribute__((ext_vector_type(4)));
typedef short short8 __attribute__((ext_vector_type(8)));

#define BB 4
#define SS 2048
#define EE 1024
#define HH 16
#define DD 64
#define NEGV (-1e9f)
#define EPSV 1e-5f

__device__ __forceinline__ u16 f2b(float x) {
  u32 u = __float_as_uint(x);
  u32 r = (u + 0x7fffu + ((u >> 16) & 1u)) >> 16;
  return (u16)r;
}
__device__ __forceinline__ float b2f(u16 u) {
  return __uint_as_float(((u32)u) << 16);
}

// ---------------- LayerNorm: 1 block per row of 1024 fp32 ----------------
template<bool OUT_BF16>
__global__ __launch_bounds__(256) void ln_kernel(const float* __restrict__ x,
    const float* __restrict__ gamma, const float* __restrict__ beta,
    void* __restrict__ outp) {
  int row = blockIdx.x;
  int t = threadIdx.x;
  const float4* xr = (const float4*)(x + (size_t)row * EE);
  float4 v = xr[t];
  float s = v.x + v.y + v.z + v.w;
  #pragma unroll
  for (int o = 1; o < 64; o <<= 1) s += __shfl_xor(s, o);
  __shared__ float red[8];
  int wid = t >> 6;
  if ((t & 63) == 0) red[wid] = s;
  __syncthreads();
  float mean = (red[0] + red[1] + red[2] + red[3]) * (1.0f / EE);
  float d0 = v.x - mean, d1 = v.y - mean, d2 = v.z - mean, d3 = v.w - mean;
  float sq = d0 * d0 + d1 * d1 + d2 * d2 + d3 * d3;
  #pragma unroll
  for (int o = 1; o < 64; o <<= 1) sq += __shfl_xor(sq, o);
  if ((t & 63) == 0) red[4 + wid] = sq;
  __syncthreads();
  float var = (red[4] + red[5] + red[6] + red[7]) * (1.0f / EE);
  float rstd = rsqrtf(var + EPSV);
  float4 g = ((const float4*)gamma)[t];
  float4 be = ((const float4*)beta)[t];
  float o0 = d0 * rstd * g.x + be.x;
  float o1 = d1 * rstd * g.y + be.y;
  float o2 = d2 * rstd * g.z + be.z;
  float o3 = d3 * rstd * g.w + be.w;
  if (OUT_BF16) {
    ushort4 pk;
    pk.x = f2b(o0); pk.y = f2b(o1); pk.z = f2b(o2); pk.w = f2b(o3);
    *(ushort4*)((u16*)outp + (size_t)row * EE + t * 4) = pk;
  } else {
    ((float4*)((float*)outp + (size_t)row * EE))[t] = make_float4(o0, o1, o2, o3);
  }
}

// ---------------- fp32 -> bf16 convert (8 elems/thread) ----------------
__global__ __launch_bounds__(256) void conv_kernel(const float* __restrict__ x,
    u16* __restrict__ y) {
  size_t i = ((size_t)blockIdx.x * 256 + threadIdx.x) * 8;
  float4 a = *(const float4*)(x + i);
  float4 c = *(const float4*)(x + i + 4);
  uint4 pk;
  pk.x = (u32)f2b(a.x) | ((u32)f2b(a.y) << 16);
  pk.y = (u32)f2b(a.z) | ((u32)f2b(a.w) << 16);
  pk.z = (u32)f2b(c.x) | ((u32)f2b(c.y) << 16);
  pk.w = (u32)f2b(c.z) | ((u32)f2b(c.w) << 16);
  *(uint4*)(y + i) = pk;
}

// ------------- W (K x N fp32) -> Wt (N x K bf16) via LDS 32x32 tile -------------
__global__ __launch_bounds__(256) void wtrans_kernel(const float* __restrict__ W,
    u16* __restrict__ Wt) {
  __shared__ float tile[32][33];
  int kb = blockIdx.x * 32, nb = blockIdx.y * 32;
  int t = threadIdx.x;
  int r = t >> 3, c = (t & 7) * 4;
  float4 v = *(const float4*)&W[(size_t)(kb + r) * EE + nb + c];
  tile[r][c] = v.x; tile[r][c + 1] = v.y; tile[r][c + 2] = v.z; tile[r][c + 3] = v.w;
  __syncthreads();
  uint2 val;
  val.x = (u32)f2b(tile[c][r]) | ((u32)f2b(tile[c + 1][r]) << 16);
  val.y = (u32)f2b(tile[c + 2][r]) | ((u32)f2b(tile[c + 3][r]) << 16);
  *(uint2*)&Wt[(size_t)(nb + r) * EE + kb + c] = val;
}

// ---------------- pack mask ints -> bit mask ----------------
__global__ __launch_bounds__(256) void maskpack_kernel(const int* __restrict__ mask,
    u64* __restrict__ mp) {
  int gid = blockIdx.x * 256 + threadIdx.x;
  int v = mask[gid];
  u64 bal = __ballot(v != 0);
  if ((threadIdx.x & 63) == 0) mp[gid >> 6] = bal;
}

// ---------------- GEMM: C = A @ Wt^T + bias (A bf16) ----------------
// MODE 0: store bf16 C[m*N+n]
// MODE 1: store bf16 transposed per-head: vt[((b*H+h)*D+d)*S + s]
// MODE 2: store fp32 C = acc + bias + residual(bf16)
template<int MODE>
__global__ __launch_bounds__(256) void gemm_kernel(const u16* __restrict__ Ap,
    const u16* __restrict__ Bt, const float* __restrict__ bias,
    const u16* __restrict__ resid, void* __restrict__ Cp) {
  constexpr int N = 1024, K = 1024;
  __shared__ u16 Al[128][40];
  __shared__ u16 Bl[128][40];
  int t = threadIdx.x;
  int lane = t & 63, wid = t >> 6;
  int mb = blockIdx.y * 128, nb = blockIdx.x * 128;
  int wm = (wid >> 1) * 64, wn = (wid & 1) * 64;
  int lrow = t >> 1, lcol = (t & 1) * 16;
  int l15 = lane & 15, lg = lane >> 4;
  int kof = lg * 8;
  f32x4 acc[4][4] = {};
  for (int kt = 0; kt < K; kt += 32) {
    {
      const u16* Ab = Ap + (size_t)(mb + lrow) * K + kt + lcol;
      *(uint4*)&Al[lrow][lcol] = *(const uint4*)Ab;
      *(uint4*)&Al[lrow][lcol + 8] = *(const uint4*)(Ab + 8);
    }
    {
      const u16* Bp = Bt + (size_t)(nb + lrow) * K + kt + lcol;
      *(uint4*)&Bl[lrow][lcol] = *(const uint4*)Bp;
      *(uint4*)&Bl[lrow][lcol + 8] = *(const uint4*)(Bp + 8);
    }
    __syncthreads();
    short8 af[4], bfv[4];
    #pragma unroll
    for (int mf = 0; mf < 4; mf++) af[mf] = *(const short8*)&Al[wm + mf * 16 + l15][kof];
    #pragma unroll
    for (int nf = 0; nf < 4; nf++) bfv[nf] = *(const short8*)&Bl[wn + nf * 16 + l15][kof];
    #pragma unroll
    for (int mf = 0; mf < 4; mf++)
      #pragma unroll
      for (int nf = 0; nf < 4; nf++)
        acc[mf][nf] = __builtin_amdgcn_mfma_f32_16x16x32_bf16(af[mf], bfv[nf], acc[mf][nf], 0, 0, 0);
    __syncthreads();
  }
  float bv[4];
  #pragma unroll
  for (int nf = 0; nf < 4; nf++) bv[nf] = bias[nb + wn + nf * 16 + l15];
  #pragma unroll
  for (int mf = 0; mf < 4; mf++) {
    #pragma unroll
    for (int r = 0; r < 4; r++) {
      int m = mb + wm + mf * 16 + lg * 4 + r;
      #pragma unroll
      for (int nf = 0; nf < 4; nf++) {
        int n = nb + wn + nf * 16 + l15;
        float val = acc[mf][nf][r] + bv[nf];
        if (MODE == 0) {
          ((u16*)Cp)[(size_t)m * N + n] = f2b(val);
        } else if (MODE == 1) {
          int b = m >> 11, s = m & 2047;
          int h = n >> 6, d = n & 63;
          ((u16*)Cp)[((size_t)((b * HH + h) * DD + d)) * SS + s] = f2b(val);
        } else {
          float rv = b2f(resid[(size_t)m * N + n]);
          ((float*)Cp)[(size_t)m * N + n] = val + rv;
        }
      }
    }
  }
}

// ---------------- flash attention, swapped-QK^T in-register softmax ----------------
// grid: (S/64, B*H); 4 waves, each owns 16 q rows (q = lane&15). KT = 64.
// LDS: K tile [64 k][64 d], V^T tile [64 d][64 k]; XOR-swizzled (16B chunk of
// row r at position c ^ (r&7)); staged via registers + ds_write_b128 (swizzle
// applied on the write side; global reads stay linear/coalesced).
__global__ __launch_bounds__(256) void attn_kernel(const u16* __restrict__ qh,
    const u16* __restrict__ kh, const u16* __restrict__ vt,
    const u64* __restrict__ mp, u16* __restrict__ outp) {
  __shared__ u16 Kl[64 * 64];
  __shared__ u16 Vl[64 * 64];
  int t = threadIdx.x, lane = t & 63, wid = t >> 6;
  int bh = blockIdx.y, b = bh >> 4, h = bh & 15;
  int qt = blockIdx.x;
  int l15 = lane & 15, lg = lane >> 4;

  // Q fragments: B-operand, lane holds Q row q=l15, d contiguous 8 at lg*8
  int qrow = qt * 64 + wid * 16 + l15;
  const u16* qbase = qh + ((size_t)(b * SS + qrow)) * EE + h * DD;
  short8 qf0 = *(const short8*)(qbase + lg * 8);
  short8 qf1 = *(const short8*)(qbase + 32 + lg * 8);
  const u64* mrow = mp + (size_t)(b * SS + qrow) * (SS / 64);

  // staging: lane handles rows r0 = wid*16+(lane>>3), r1 = r0+8; global chunk cc = lane&7
  int r0 = wid * 16 + (lane >> 3);
  int r1 = r0 + 8;
  int cc = lane & 7;
  int wk0 = r0 * 64 + ((cc ^ (r0 & 7)) * 8);   // u16 offset of swizzled chunk
  int wk1 = r1 * 64 + ((cc ^ (r1 & 7)) * 8);
  const u16* kgb = kh + ((size_t)b * SS) * EE + h * DD;
  const u16* vgb = vt + ((size_t)bh * DD) * SS;

  f32x4 O[4] = {};
  float mi = -3.0e38f, li = 0.f;
  constexpr int NT = SS / 64;

  // preload tile 0 into registers
  uint4 sk0 = *(const uint4*)(kgb + (size_t)r0 * EE + cc * 8);
  uint4 sk1 = *(const uint4*)(kgb + (size_t)r1 * EE + cc * 8);
  uint4 sv0 = *(const uint4*)(vgb + (size_t)r0 * SS + cc * 8);
  uint4 sv1 = *(const uint4*)(vgb + (size_t)r1 * SS + cc * 8);

  for (int kt = 0; kt < NT; ++kt) {
    // write staged tile to swizzled LDS (previous iteration's reads done at loop-end barrier)
    *(uint4*)&Kl[wk0] = sk0;
    *(uint4*)&Kl[wk1] = sk1;
    *(uint4*)&Vl[wk0] = sv0;
    *(uint4*)&Vl[wk1] = sv1;
    __syncthreads();

    // prefetch next tile (clamped on last iteration; values unused then)
    int nk = (kt + 1 < NT) ? kt + 1 : kt;
    sk0 = *(const uint4*)(kgb + (size_t)(nk * 64 + r0) * EE + cc * 8);
    sk1 = *(const uint4*)(kgb + (size_t)(nk * 64 + r1) * EE + cc * 8);
    sv0 = *(const uint4*)(vgb + (size_t)r0 * SS + nk * 64 + cc * 8);
    sv1 = *(const uint4*)(vgb + (size_t)r1 * SS + nk * 64 + cc * 8);

    // QK^T swapped: sc[nf][r] = S^T[k = nf*16 + lg*4 + r][q = l15]
    f32x4 sc[4];
    #pragma unroll
    for (int nf = 0; nf < 4; nf++) {
      int row = nf * 16 + l15;
      short8 k0 = *(const short8*)&Kl[row * 64 + ((lg ^ (row & 7)) * 8)];
      short8 k1 = *(const short8*)&Kl[row * 64 + (((4 + lg) ^ (row & 7)) * 8)];
      f32x4 z = {};
      z = __builtin_amdgcn_mfma_f32_16x16x32_bf16(k0, qf0, z, 0, 0, 0);
      z = __builtin_amdgcn_mfma_f32_16x16x32_bf16(k1, qf1, z, 0, 0, 0);
      sc[nf] = z;
    }

    // mask: bit (nf*16 + lg*4 + r) of this q-row's word
    u64 mw = mrow[kt];
    #pragma unroll
    for (int nf = 0; nf < 4; nf++) {
      u32 nib = (u32)(mw >> (nf * 16 + lg * 4)) & 15u;
      #pragma unroll
      for (int r = 0; r < 4; r++)
        if (nib & (1u << r)) sc[nf][r] = NEGV;
    }

    // online softmax, per-lane row (q = l15), reduce across lg via xor 16/32
    float mx = fmaxf(fmaxf(fmaxf(sc[0][0], sc[0][1]), fmaxf(sc[0][2], sc[0][3])),
                     fmaxf(fmaxf(sc[1][0], sc[1][1]), fmaxf(sc[1][2], sc[1][3])));
    float mx2 = fmaxf(fmaxf(fmaxf(sc[2][0], sc[2][1]), fmaxf(sc[2][2], sc[2][3])),
                      fmaxf(fmaxf(sc[3][0], sc[3][1]), fmaxf(sc[3][2], sc[3][3])));
    mx = fmaxf(mx, mx2);
    mx = fmaxf(mx, __shfl_xor(mx, 16));
    mx = fmaxf(mx, __shfl_xor(mx, 32));
    float mnew = fmaxf(mi, mx);
    float scale = __expf(mi - mnew);
    float rs = 0.f;
    #pragma unroll
    for (int nf = 0; nf < 4; nf++) {
      #pragma unroll
      for (int r = 0; r < 4; r++) {
        float p = __expf(sc[nf][r] - mnew);
        sc[nf][r] = p;
        rs += p;
      }
    }
    rs += __shfl_xor(rs, 16);
    rs += __shfl_xor(rs, 32);
    li = li * scale + rs;
    mi = mnew;

    // rescale O (O reg r of any frag belongs to q = lg*4 + r)
    float sb[4];
    #pragma unroll
    for (int r = 0; r < 4; r++) sb[r] = __shfl(scale, lg * 4 + r);
    #pragma unroll
    for (int nf = 0; nf < 4; nf++)
      #pragma unroll
      for (int r = 0; r < 4; r++) O[nf][r] *= sb[r];

    // pack P to bf16 pairs: pk2[nf][hi] = (p[2hi], p[2hi+1]) for q=l15
    u32 pk2[4][2];
    #pragma unroll
    for (int nf = 0; nf < 4; nf++) {
      pk2[nf][0] = (u32)f2b(sc[nf][0]) | ((u32)f2b(sc[nf][1]) << 16);
      pk2[nf][1] = (u32)f2b(sc[nf][2]) | ((u32)f2b(sc[nf][3]) << 16);
    }
    // redistribute to PV A-fragment layout: lane (l15,lg) needs P[q=l15][k=f*32+lg*8+j]
    u32 av0[4], av1[4];
    #pragma unroll
    for (int w = 0; w < 4; w++) {
      int srcl = l15 + 16 * ((lg * 2 + (w >> 1)) & 3);
      u32 a0 = __shfl(pk2[0][w & 1], srcl);
      u32 b0 = __shfl(pk2[1][w & 1], srcl);
      av0[w] = (lg & 2) ? b0 : a0;
      u32 a1 = __shfl(pk2[2][w & 1], srcl);
      u32 b1 = __shfl(pk2[3][w & 1], srcl);
      av1[w] = (lg & 2) ? b1 : a1;
    }
    short8 pa0, pa1;
    #pragma unroll
    for (int w = 0; w < 4; w++) {
      ((u32*)&pa0)[w] = av0[w];
      ((u32*)&pa1)[w] = av1[w];
    }

    // PV: O[q][d] += P[q][k] * V^T[d][k]
    #pragma unroll
    for (int nf = 0; nf < 4; nf++) {
      int row = nf * 16 + l15;
      short8 v0 = *(const short8*)&Vl[row * 64 + ((lg ^ (row & 7)) * 8)];
      short8 v1 = *(const short8*)&Vl[row * 64 + (((4 + lg) ^ (row & 7)) * 8)];
      O[nf] = __builtin_amdgcn_mfma_f32_16x16x32_bf16(pa0, v0, O[nf], 0, 0, 0);
      O[nf] = __builtin_amdgcn_mfma_f32_16x16x32_bf16(pa1, v1, O[nf], 0, 0, 0);
    }
    __syncthreads();
  }

  float inv = 1.0f / li;
  float ib[4];
  #pragma unroll
  for (int r = 0; r < 4; r++) ib[r] = __shfl(inv, lg * 4 + r);
  #pragma unroll
  for (int r = 0; r < 4; r++) {
    int qr = qt * 64 + wid * 16 + lg * 4 + r;
    #pragma unroll
    for (int nf = 0; nf < 4; nf++) {
      outp[((size_t)(b * SS + qr)) * EE + h * DD + nf * 16 + l15] = f2b(O[nf][r] * ib[r]);
    }
  }
}

extern "C" void kernel_launch(void* const* d_in, const int* in_sizes, int n_in,
                              void* d_out, int out_size, void* d_ws, size_t ws_size,
                              hipStream_t stream) {
  (void)in_sizes; (void)n_in; (void)out_size; (void)ws_size;
  const float* q    = (const float*)d_in[0];
  const float* k    = (const float*)d_in[1];
  const float* v    = (const float*)d_in[2];
  const int*   mask = (const int*)d_in[3];
  const float* W1   = (const float*)d_in[4];
  const float* b1   = (const float*)d_in[5];
  const float* W2   = (const float*)d_in[6];
  const float* b2   = (const float*)d_in[7];
  const float* W3   = (const float*)d_in[8];
  const float* b3   = (const float*)d_in[9];
  const float* W4   = (const float*)d_in[10];
  const float* b4   = (const float*)d_in[11];
  const float* gamma = (const float*)d_in[12];
  const float* beta  = (const float*)d_in[13];
  float* out = (float*)d_out;
  char* ws = (char*)d_ws;
  const size_t MB = 1024 * 1024;
  u16* qh  = (u16*)(ws + 0 * MB);
  u16* kh  = (u16*)(ws + 16 * MB);
  u16* vt  = (u16*)(ws + 32 * MB);
  u16* ao  = (u16*)(ws + 48 * MB);   // also reused early as qk bf16 staging
  u16* vn  = (u16*)(ws + 64 * MB);
  u16* W1t = (u16*)(ws + 80 * MB);
  u16* W2t = (u16*)(ws + 82 * MB);
  u16* W3t = (u16*)(ws + 84 * MB);
  u16* W4t = (u16*)(ws + 86 * MB);
  u64* mp  = (u64*)(ws + 88 * MB);
  float* tmp = (float*)(ws + 0 * MB);  // overlays qh+kh (dead by then)
  u16* qkb = ao;  // 16MB bf16 staging for converted q/k (dead before attn writes ao)

  wtrans_kernel<<<dim3(32, 32), 256, 0, stream>>>(W1, W1t);
  wtrans_kernel<<<dim3(32, 32), 256, 0, stream>>>(W2, W2t);
  wtrans_kernel<<<dim3(32, 32), 256, 0, stream>>>(W3, W3t);
  wtrans_kernel<<<dim3(32, 32), 256, 0, stream>>>(W4, W4t);
  maskpack_kernel<<<65536, 256, 0, stream>>>(mask, mp);
  ln_kernel<true><<<8192, 256, 0, stream>>>(v, gamma, beta, vn);
  conv_kernel<<<4096, 256, 0, stream>>>(q, qkb);
  gemm_kernel<0><<<dim3(8, 64), 256, 0, stream>>>(qkb, W1t, b1, nullptr, qh);
  conv_kernel<<<4096, 256, 0, stream>>>(k, qkb);
  gemm_kernel<0><<<dim3(8, 64), 256, 0, stream>>>(qkb, W2t, b2, nullptr, kh);
  gemm_kernel<1><<<dim3(8, 64), 256, 0, stream>>>(vn, W3t, b3, nullptr, vt);
  attn_kernel<<<dim3(32, 64), 256, 0, stream>>>(qh, kh, vt, mp, ao);
  gemm_kernel<2><<<dim3(8, 64), 256, 0, stream>>>(ao, W4t, b4, vn, tmp);
  ln_kernel<false><<<8192, 256, 0, stream>>>(tmp, gamma, beta, out);
}